// Round 7
// baseline (2896.020 us; speedup 1.0000x reference)
//
#include <hip/hip_runtime.h>

typedef unsigned short u16;

#define DEV static __device__ __forceinline__

DEV double ld_d(const float* p, int i) { return (double)p[i]; }

// ---------------------------------------------------------------- encoder ---

struct EncW {
  const float* cw[4]; const float* cb[4]; const float* g[4]; const float* bt[4];
  const float* rw[4]; const float* rb[4]; const float* rg[4]; const float* rbt[4];
};

// One GCN layer, all-f64 activations, in-place in a single 64x220 f64 buffer.
// act layout: [c][t*22+v], stride 220 doubles per channel.
// Weights staged as f32 (bit-exact copies of f32 inputs), converted on use.
template<int CI, int CO>
DEV void gcn_layer64(int tid,
    const float* __restrict__ cw, const float* __restrict__ cb,
    const float* __restrict__ gg, const float* __restrict__ bt,
    const float* __restrict__ rw, const float* __restrict__ rb,
    const float* __restrict__ rg, const float* __restrict__ rbt,
    const float* __restrict__ TmL, const float* __restrict__ AL, double preL,
    double* __restrict__ act,
    float* __restrict__ wT, float* __restrict__ TmTs, float* __restrict__ ATf,
    double* __restrict__ rmul, double* __restrict__ radd,
    double* __restrict__ cmul, double* __restrict__ cadd)
{
  constexpr int COP8 = (CO + 7) & ~7;         // 8, 32, or 64
  constexpr int NT = (COP8 / 8) * 55;         // o-oct x p-quad tasks (<=440)
  const double SQ = sqrt(1.0 + 1e-5);

  // ---- phase 1: stage residual weights (transposed), BN consts, Tm, A ----
  for (int idx = tid; idx < CI * 64; idx += 512) {
    int c = idx / 64, o = idx % 64;
    wT[idx] = (o < CO) ? rw[o * CI + c] : 0.f;
  }
  for (int idx = tid; idx < 64; idx += 512) {
    bool ok = idx < CO;
    double rm = ok ? ld_d(rg, idx) / SQ : 0.0;
    double cm = ok ? ld_d(gg, idx) / SQ : 0.0;
    rmul[idx] = rm;
    radd[idx] = ok ? ld_d(rb, idx) * rm + ld_d(rbt, idx) : 0.0;
    cmul[idx] = cm;
    cadd[idx] = ok ? ld_d(cb, idx) * cm + ld_d(bt, idx) : 0.0;
  }
  // TmTs[(t*10+q)*22+v] = Tm[v*100+t*10+q]
  for (int idx = tid; idx < 2200; idx += 512) {
    int tq = idx / 22, v = idx % 22;
    int t = tq / 10, q = tq % 10;
    TmTs[idx] = TmL[v * 100 + t * 10 + q];
  }
  // ATf identical layout to A[t][v][w]
  for (int idx = tid; idx < 4840; idx += 512) ATf[idx] = AL[idx];
  __syncthreads();

  // ---- phase 2a: residual channel-mix -> registers (BN applied) ----
  double racc[32];
  int oo = tid / 55, pp = tid % 55;     // valid when tid < NT
  if (tid < NT) {
    #pragma unroll
    for (int k = 0; k < 32; ++k) racc[k] = 0.0;
    #pragma unroll 4
    for (int c = 0; c < CI; ++c) {
      const float* wr = wT + c * 64 + oo * 8;
      const double* ar = act + c * 220 + pp * 4;
      double a0 = ar[0], a1 = ar[1], a2 = ar[2], a3 = ar[3];
      #pragma unroll
      for (int o = 0; o < 8; ++o) {
        double w = (double)wr[o];
        racc[o * 4 + 0] += w * a0; racc[o * 4 + 1] += w * a1;
        racc[o * 4 + 2] += w * a2; racc[o * 4 + 3] += w * a3;
      }
    }
    #pragma unroll
    for (int o = 0; o < 8; ++o) {
      double m = rmul[oo * 8 + o], a = radd[oo * 8 + o];
      #pragma unroll
      for (int k = 0; k < 4; ++k) racc[o * 4 + k] = racc[o * 4 + k] * m + a;
    }
  }
  __syncthreads();

  // ---- phase 2b: temporal mix, in place (column-pair private) ----
  for (int idx = tid; idx < CI * 11; idx += 512) {
    int c = idx % CI, v2 = idx / CI;
    double* base = act + c * 220 + v2 * 2;
    double xin[10][2];
    #pragma unroll
    for (int t = 0; t < 10; ++t) { xin[t][0] = base[t * 22]; xin[t][1] = base[t * 22 + 1]; }
    double ya[10][2];
    #pragma unroll
    for (int q = 0; q < 10; ++q) { ya[q][0] = 0.0; ya[q][1] = 0.0; }
    #pragma unroll
    for (int t = 0; t < 10; ++t) {
      const float* tm = TmTs + t * 220 + v2 * 2;   // (t*10+q)*22 + v
      #pragma unroll
      for (int q = 0; q < 10; ++q) {
        ya[q][0] += (double)tm[q * 22]     * xin[t][0];
        ya[q][1] += (double)tm[q * 22 + 1] * xin[t][1];
      }
    }
    #pragma unroll
    for (int q = 0; q < 10; ++q) { base[q * 22] = ya[q][0]; base[q * 22 + 1] = ya[q][1]; }
  }
  __syncthreads();

  // ---- phase 3: spatial mix, in place (row private); restage wT <- cw ----
  for (int idx = tid; idx < CI * 10; idx += 512) {
    int c = idx % CI, t = idx / CI;
    double* row = act + c * 220 + t * 22;
    double yin[22];
    #pragma unroll
    for (int v = 0; v < 22; ++v) yin[v] = row[v];
    double za[22];
    #pragma unroll
    for (int w = 0; w < 22; ++w) za[w] = 0.0;
    #pragma unroll 2
    for (int v = 0; v < 22; ++v) {
      const float* ar = ATf + (t * 22 + v) * 22;
      double y0 = yin[v];
      #pragma unroll
      for (int w = 0; w < 22; ++w) za[w] += y0 * (double)ar[w];
    }
    #pragma unroll
    for (int w = 0; w < 22; ++w) row[w] = za[w];
  }
  for (int idx = tid; idx < CI * 64; idx += 512) {
    int c = idx / 64, o = idx % 64;
    wT[idx] = (o < CO) ? cw[o * CI + c] : 0.f;
  }
  __syncthreads();

  // ---- phase 4: main channel-mix into registers, barrier, in-place write ----
  double cacc[32];
  if (tid < NT) {
    #pragma unroll
    for (int k = 0; k < 32; ++k) cacc[k] = 0.0;
    #pragma unroll 4
    for (int c = 0; c < CI; ++c) {
      const float* wr = wT + c * 64 + oo * 8;
      const double* ar = act + c * 220 + pp * 4;
      double a0 = ar[0], a1 = ar[1], a2 = ar[2], a3 = ar[3];
      #pragma unroll
      for (int o = 0; o < 8; ++o) {
        double w = (double)wr[o];
        cacc[o * 4 + 0] += w * a0; cacc[o * 4 + 1] += w * a1;
        cacc[o * 4 + 2] += w * a2; cacc[o * 4 + 3] += w * a3;
      }
    }
  }
  __syncthreads();   // all reads of act complete before overwrite
  if (tid < NT) {
    #pragma unroll
    for (int o = 0; o < 8; ++o) {
      double m = cmul[oo * 8 + o], a = cadd[oo * 8 + o];
      #pragma unroll
      for (int k = 0; k < 4; ++k) {
        double y = cacc[o * 4 + k] * m + a + racc[o * 4 + k];
        act[(oo * 8 + o) * 220 + pp * 4 + k] = (y >= 0.0) ? y : preL * y;
      }
    }
  }
  __syncthreads();
}

__global__ __launch_bounds__(512, 2)
void enc_kernel(const float* __restrict__ x, const float* __restrict__ A,
                const float* __restrict__ Tm, const float* __restrict__ pre, EncW W,
                const float* __restrict__ qkvT, const float* __restrict__ qkv_b,
                double* __restrict__ h0_ws, double* __restrict__ k_ws,
                double* __restrict__ v_ws)
{
  __shared__ __align__(16) double act[64 * 220];     // 112640 B
  __shared__ __align__(16) float wT[64 * 64];        //  16384 B
  __shared__ __align__(16) float TmTs[2200];         //   8800 B
  __shared__ __align__(16) float ATf[4840];          //  19360 B
  __shared__ double rmul[64], radd[64], cmul[64], cadd[64];  // 2048 B

  const int tid = threadIdx.x;
  const int b = blockIdx.x;

  // load x[b] -> act[c][t*22+v] (f64, exact)
  for (int idx = tid; idx < 660; idx += 512) {
    int c = idx / 220, r = idx % 220, t = r / 22, v = r % 22;
    act[c * 220 + t * 22 + v] = (double)x[(((size_t)b * 10 + t) * 22 + v) * 3 + c];
  }
  double p0 = (double)pre[0], p1 = (double)pre[1];
  double p2 = (double)pre[2], p3 = (double)pre[3];

  gcn_layer64<3, 64>(tid, W.cw[0], W.cb[0], W.g[0], W.bt[0], W.rw[0], W.rb[0], W.rg[0], W.rbt[0],
                     Tm, A, p0, act, wT, TmTs, ATf, rmul, radd, cmul, cadd);
  gcn_layer64<64, 32>(tid, W.cw[1], W.cb[1], W.g[1], W.bt[1], W.rw[1], W.rb[1], W.rg[1], W.rbt[1],
                     Tm + 2200, A + 4840, p1, act, wT, TmTs, ATf, rmul, radd, cmul, cadd);
  gcn_layer64<32, 64>(tid, W.cw[2], W.cb[2], W.g[2], W.bt[2], W.rw[2], W.rb[2], W.rg[2], W.rbt[2],
                     Tm + 4400, A + 9680, p2, act, wT, TmTs, ATf, rmul, radd, cmul, cadd);
  gcn_layer64<64, 3>(tid, W.cw[3], W.cb[3], W.g[3], W.bt[3], W.rw[3], W.rb[3], W.rg[3], W.rbt[3],
                     Tm + 6600, A + 14520, p3, act, wT, TmTs, ATf, rmul, radd, cmul, cadd);
  // final activations: act rows 0..2

  // build encD[t][d = v*3+c] in act rows 3..5 (660 doubles); store h0
  double* encD = act + 3 * 220;
  for (int idx = tid; idx < 660; idx += 512) {
    int t = idx / 66, d = idx % 66, v = d / 3, c = d % 3;
    double val = act[c * 220 + t * 22 + v];
    encD[idx] = val;
    if (t == 9) h0_ws[(size_t)b * 66 + d] = val;
  }
  __syncthreads();

  // K/V projection (f64): qkvT[e*198 + j], rows j=66..131 -> k, 132..197 -> v
  for (int idx = tid; idx < 132; idx += 512) {
    int half = idx / 66, d = idx % 66;
    int row = 66 + half * 66 + d;
    double acc[10];
    #pragma unroll
    for (int t = 0; t < 10; ++t) acc[t] = 0.0;
    for (int e = 0; e < 66; ++e) {
      double w = (double)qkvT[e * 198 + row];
      const double* er = encD + e;
      #pragma unroll
      for (int t = 0; t < 10; ++t) acc[t] += w * er[t * 66];
    }
    double bias = ld_d(qkv_b, row);
    double* dst = (half ? v_ws : k_ws) + (size_t)b * 660 + d;
    #pragma unroll
    for (int t = 0; t < 10; ++t) dst[t * 66] = acc[t] + bias;
  }
}

// --------------------------------------------- prep: exact f32 transposes ---

__global__ __launch_bounds__(512)
void prep_kernel(const float* __restrict__ qkv_w, const float* __restrict__ ow,
                 const float* __restrict__ lw,
                 float* __restrict__ qkvT, float* __restrict__ owT,
                 float* __restrict__ lwAT, float* __restrict__ lwBT)
{
  int idx = blockIdx.x * 512 + threadIdx.x;
  if (idx < 13068) {                 // qkvT[e*198+j] = qkv_w[j*66+e]
    int e = idx / 198, j = idx % 198;
    qkvT[idx] = qkv_w[j * 66 + e];
  }
  int i2 = idx - 13068;
  if (i2 >= 0 && i2 < 4356) {        // owT[e*66+j] = ow[j*66+e]
    int e = i2 / 66, j = i2 % 66;
    owT[i2] = ow[j * 66 + e];
  }
  int i3 = i2 - 4356;
  if (i3 >= 0 && i3 < 4356) {        // lwAT[e*66+d] = lw[d*132+e]
    int e = i3 / 66, d = i3 % 66;
    lwAT[i3] = lw[d * 132 + e];
  }
  int i4 = i3 - 4356;
  if (i4 >= 0 && i4 < 4356) {        // lwBT[e*66+d] = lw[d*132+66+e]
    int e = i4 / 66, d = i4 % 66;
    lwBT[i4] = lw[d * 132 + 66 + e];
  }
}

// ---------------------------------------------------------------- decoder ---
// NOTE: 8 rows x 66 dims = 528 tasks > 512 threads. Every per-step phase that
// iterates row-dim tasks MUST be a block-stride loop (the `if (tid < 528)`
// guard silently dropped tasks 512..527 = row 7, dims 50..65 — the R2..R6 bug).

__global__ __launch_bounds__(512, 2)
void dec_kernel(const float* __restrict__ x, const double* __restrict__ h0_ws,
                const double* __restrict__ k_ws, const double* __restrict__ v_ws,
                const float* __restrict__ gru_wi, const float* __restrict__ gru_wh,
                const float* __restrict__ gru_bi, const float* __restrict__ gru_bh,
                const float* __restrict__ qkvT, const float* __restrict__ qkv_b,
                const float* __restrict__ owT, const float* __restrict__ ob,
                const float* __restrict__ lwAT, const float* __restrict__ lwBT,
                const float* __restrict__ lb,
                float* __restrict__ outp)
{
  __shared__ __align__(16) float wiS[198 * 68];      // 53856 B
  __shared__ __align__(16) float whS[198 * 68];      // 53856 B
  __shared__ __align__(16) double hsS[8 * 68];
  __shared__ __align__(16) double tpS[8 * 68];
  __shared__ __align__(16) double qbS[8 * 68];
  __shared__ __align__(16) double cxS[8 * 68];
  __shared__ __align__(16) double c2S[8 * 68];
  __shared__ __align__(16) double giS[8 * 198];
  __shared__ __align__(16) double ghS[8 * 198];
  __shared__ double attnS[240];

  const int tid = threadIdx.x;
  const int b0 = blockIdx.x * 8;

  for (int idx = tid; idx < 198 * 68; idx += 512) {
    int j = idx / 68, e = idx % 68;
    bool ok = e < 66;
    wiS[idx] = ok ? gru_wi[j * 66 + e] : 0.f;
    whS[idx] = ok ? gru_wh[j * 66 + e] : 0.f;
  }
  for (int idx = tid; idx < 8 * 68; idx += 512) {
    int r = idx / 68, e = idx % 68;
    size_t b = (size_t)(b0 + r);
    hsS[idx] = (e < 66) ? h0_ws[b * 66 + e] : 0.0;
    tpS[idx] = (e < 66) ? (double)x[b * 660 + 594 + e] : 0.0;
    qbS[idx] = 0.0; cxS[idx] = 0.0; c2S[idx] = 0.0;
  }
  __syncthreads();

  const double qscale = 1.0 / (double)sqrtf(22.0f);

  for (int s = 0; s < 25; ++s) {
    // P1: gi = tp@wi.T + bi ; gh = hs@wh.T + bh   (396 tasks, fits)
    if (tid < 396) {
      int kind = tid / 198, j = tid % 198;
      const float* wr = (kind ? whS : wiS) + j * 68;
      const double* actp = kind ? hsS : tpS;
      double acc[8];
      #pragma unroll
      for (int r = 0; r < 8; ++r) acc[r] = 0.0;
      #pragma unroll
      for (int e2 = 0; e2 < 33; ++e2) {
        double w0 = (double)wr[e2 * 2];
        double w1 = (double)wr[e2 * 2 + 1];
        #pragma unroll
        for (int r = 0; r < 8; ++r) {
          const double* a = actp + r * 68 + e2 * 2;
          acc[r] += w0 * a[0] + w1 * a[1];
        }
      }
      double bias = (double)(kind ? gru_bh[j] : gru_bi[j]);
      double* dst = kind ? ghS : giS;
      #pragma unroll
      for (int r = 0; r < 8; ++r) dst[r * 198 + j] = acc[r] + bias;
    }
    __syncthreads();

    // P2: GRU gates -> new hs (528 tasks -> block-stride)
    for (int idx = tid; idx < 528; idx += 512) {
      int r = idx / 66, d = idx % 66;
      const double* gir = giS + r * 198;
      const double* ghr = ghS + r * 198;
      double rg = 1.0 / (1.0 + exp(-(gir[d] + ghr[d])));
      double zg = 1.0 / (1.0 + exp(-(gir[66 + d] + ghr[66 + d])));
      double ng = tanh(gir[132 + d] + rg * ghr[132 + d]);
      double h = hsS[r * 68 + d];
      hsS[r * 68 + d] = (1.0 - zg) * ng + zg * h;
    }
    __syncthreads();

    // P3: q = (hs@wq.T + bq)*scale (528 tasks -> block-stride)
    for (int idx = tid; idx < 528; idx += 512) {
      int r = idx / 66, d = idx % 66;
      const double* ar = hsS + r * 68;
      double acc = 0.0;
      for (int e = 0; e < 66; ++e)
        acc += (double)qkvT[e * 198 + d] * ar[e];
      qbS[r * 68 + d] = (acc + (double)qkv_b[d]) * qscale;
    }
    __syncthreads();

    // P4a: scores (240 tasks)
    if (tid < 240) {
      int r = tid / 30, rem = tid % 30, h = rem / 10, t = rem % 10;
      const double* kp = k_ws + ((size_t)(b0 + r) * 10 + t) * 66 + h * 22;
      const double* qp = qbS + r * 68 + h * 22;
      double acc = 0.0;
      #pragma unroll
      for (int dd = 0; dd < 22; ++dd) acc += qp[dd] * kp[dd];
      attnS[(r * 3 + h) * 10 + t] = acc;
    }
    __syncthreads();

    // P4b: softmax over t (24 tasks)
    if (tid < 24) {
      double* sp = attnS + tid * 10;
      double mx = sp[0];
      #pragma unroll
      for (int t = 1; t < 10; ++t) mx = fmax(mx, sp[t]);
      double sum = 0.0;
      #pragma unroll
      for (int t = 0; t < 10; ++t) { double e = exp(sp[t] - mx); sp[t] = e; sum += e; }
      double invs = 1.0 / sum;
      #pragma unroll
      for (int t = 0; t < 10; ++t) sp[t] *= invs;
    }
    __syncthreads();

    // P5: raw ctx = attn @ v (528 tasks -> block-stride)
    for (int idx = tid; idx < 528; idx += 512) {
      int r = idx / 66, d = idx % 66, h = d / 22;
      const double* ap = attnS + (r * 3 + h) * 10;
      const double* vp = v_ws + (size_t)(b0 + r) * 660 + d;
      double acc = 0.0;
      #pragma unroll
      for (int t = 0; t < 10; ++t) acc += ap[t] * vp[t * 66];
      cxS[r * 68 + d] = acc;
    }
    __syncthreads();

    // P6: ctx2 = rawctx @ ow.T + ob (528 tasks -> block-stride)
    for (int idx = tid; idx < 528; idx += 512) {
      int r = idx / 66, j = idx % 66;
      const double* cr = cxS + r * 68;
      double acc = 0.0;
      for (int e = 0; e < 66; ++e)
        acc += (double)owT[e * 66 + j] * cr[e];
      c2S[r * 68 + j] = acc + (double)ob[j];
    }
    __syncthreads();

    // P7: pred = lwA@hs + lwB@ctx2 + lb + tp (528 tasks -> block-stride)
    for (int idx = tid; idx < 528; idx += 512) {
      int r = idx / 66, d = idx % 66;
      const double* hr = hsS + r * 68;
      const double* c2 = c2S + r * 68;
      double acc = 0.0;
      for (int e = 0; e < 66; ++e)
        acc += (double)lwAT[e * 66 + d] * hr[e];
      double acc2 = 0.0;
      for (int e = 0; e < 66; ++e)
        acc2 += (double)lwBT[e * 66 + d] * c2[e];
      double pred = acc + acc2 + (double)lb[d] + tpS[r * 68 + d];
      outp[((size_t)(b0 + r) * 25 + s) * 66 + d] = (float)pred;
      tpS[r * 68 + d] = pred;
    }
    __syncthreads();
  }
}

// ----------------------------------------------------------------- launch ---

extern "C" void kernel_launch(void* const* d_in, const int* in_sizes, int n_in,
                              void* d_out, int out_size, void* d_ws, size_t ws_size,
                              hipStream_t stream) {
  (void)in_sizes; (void)n_in; (void)out_size; (void)ws_size;
  const float* x   = (const float*)d_in[0];
  const float* A   = (const float*)d_in[1];
  const float* Tm  = (const float*)d_in[2];
  const float* pre = (const float*)d_in[3];
  EncW W;
  for (int i = 0; i < 4; ++i) {
    W.cw[i]  = (const float*)d_in[4 + 8 * i + 0];
    W.cb[i]  = (const float*)d_in[4 + 8 * i + 1];
    W.g[i]   = (const float*)d_in[4 + 8 * i + 2];
    W.bt[i]  = (const float*)d_in[4 + 8 * i + 3];
    W.rw[i]  = (const float*)d_in[4 + 8 * i + 4];
    W.rb[i]  = (const float*)d_in[4 + 8 * i + 5];
    W.rg[i]  = (const float*)d_in[4 + 8 * i + 6];
    W.rbt[i] = (const float*)d_in[4 + 8 * i + 7];
  }
  const float* gru_wi = (const float*)d_in[36];
  const float* gru_wh = (const float*)d_in[37];
  const float* gru_bi = (const float*)d_in[38];
  const float* gru_bh = (const float*)d_in[39];
  const float* qkv_w  = (const float*)d_in[40];
  const float* qkv_b  = (const float*)d_in[41];
  const float* ow     = (const float*)d_in[42];
  const float* ob     = (const float*)d_in[43];
  const float* lw     = (const float*)d_in[44];
  const float* lb     = (const float*)d_in[45];

  double* wsd  = (double*)d_ws;
  double* h0   = wsd;                       // 2048*66 f64
  double* kw   = h0 + 2048 * 66;            // 2048*660 f64
  double* vw   = kw + 2048 * 660;           // 2048*660 f64
  float*  fws  = (float*)(vw + 2048 * 660);
  float*  qkvT = fws;                       // 13068 f32
  float*  owT  = qkvT + 13068;              // 4356
  float*  lwAT = owT + 4356;                // 4356
  float*  lwBT = lwAT + 4356;               // 4356

  prep_kernel<<<52, 512, 0, stream>>>(qkv_w, ow, lw, qkvT, owT, lwAT, lwBT);
  enc_kernel<<<2048, 512, 0, stream>>>(x, A, Tm, pre, W, qkvT, qkv_b, h0, kw, vw);
  dec_kernel<<<256, 512, 0, stream>>>(x, h0, kw, vw, gru_wi, gru_wh, gru_bi, gru_bh,
                                      qkvT, qkv_b, owT, ob, lwAT, lwBT, lb,
                                      (float*)d_out);
}

// Round 8
// 982.766 us; speedup vs baseline: 2.9468x; 2.9468x over previous
//
#include <hip/hip_runtime.h>

#define DEV static __device__ __forceinline__

// ---------------------------------------------------------------- encoder ---

struct EncW {
  const float* cw[4]; const float* cb[4]; const float* g[4]; const float* bt[4];
  const float* rw[4]; const float* rb[4]; const float* rg[4]; const float* rbt[4];
};

// One GCN layer, f32 activations, in-place in a single 64x220 buffer.
// act layout: [c][t*22+v], stride 220 floats per channel.
template<int CI, int CO>
DEV void gcn_layer32(int tid,
    const float* __restrict__ cw, const float* __restrict__ cb,
    const float* __restrict__ gg, const float* __restrict__ bt,
    const float* __restrict__ rw, const float* __restrict__ rb,
    const float* __restrict__ rg, const float* __restrict__ rbt,
    const float* __restrict__ TmL, const float* __restrict__ AL, float preL,
    float* __restrict__ act,
    float* __restrict__ wT, float* __restrict__ TmTs, float* __restrict__ ATf,
    float* __restrict__ rmul, float* __restrict__ radd,
    float* __restrict__ cmul, float* __restrict__ cadd)
{
  constexpr int COP8 = (CO + 7) & ~7;         // 8, 32, or 64
  constexpr int NT = (COP8 / 8) * 55;         // o-oct x p-quad tasks (<=440)
  const float inv = 0.99999499987f;           // 1/sqrt(1+1e-5)

  // ---- phase 1: stage residual weights (transposed), BN consts, Tm, A ----
  for (int idx = tid; idx < CI * 64; idx += 512) {
    int c = idx / 64, o = idx % 64;
    wT[idx] = (o < CO) ? rw[o * CI + c] : 0.f;
  }
  for (int idx = tid; idx < 64; idx += 512) {
    bool ok = idx < CO;
    float rm = ok ? rg[idx] * inv : 0.f;
    float cm = ok ? gg[idx] * inv : 0.f;
    rmul[idx] = rm;
    radd[idx] = ok ? rb[idx] * rm + rbt[idx] : 0.f;
    cmul[idx] = cm;
    cadd[idx] = ok ? cb[idx] * cm + bt[idx] : 0.f;
  }
  // TmTs[(t*10+q)*22+v] = Tm[v*100+t*10+q]
  for (int idx = tid; idx < 2200; idx += 512) {
    int tq = idx / 22, v = idx % 22;
    int t = tq / 10, q = tq % 10;
    TmTs[idx] = TmL[v * 100 + t * 10 + q];
  }
  for (int idx = tid; idx < 4840; idx += 512) ATf[idx] = AL[idx];
  __syncthreads();

  // ---- phase 2a: residual channel-mix -> registers (BN applied) ----
  float racc[32];
  int oo = tid / 55, pp = tid % 55;     // valid when tid < NT
  if (tid < NT) {
    #pragma unroll
    for (int k = 0; k < 32; ++k) racc[k] = 0.f;
    #pragma unroll 4
    for (int c = 0; c < CI; ++c) {
      const float* wr = wT + c * 64 + oo * 8;
      float4 w0 = *(const float4*)(wr);
      float4 w1 = *(const float4*)(wr + 4);
      float4 av = *(const float4*)(act + c * 220 + pp * 4);
      float wv[8] = {w0.x,w0.y,w0.z,w0.w,w1.x,w1.y,w1.z,w1.w};
      #pragma unroll
      for (int o = 0; o < 8; ++o) {
        racc[o*4+0] += wv[o]*av.x; racc[o*4+1] += wv[o]*av.y;
        racc[o*4+2] += wv[o]*av.z; racc[o*4+3] += wv[o]*av.w;
      }
    }
    #pragma unroll
    for (int o = 0; o < 8; ++o) {
      float m = rmul[oo * 8 + o], a = radd[oo * 8 + o];
      #pragma unroll
      for (int k = 0; k < 4; ++k) racc[o*4+k] = racc[o*4+k]*m + a;
    }
  }
  __syncthreads();

  // ---- phase 2b: temporal mix, in place (column-pair private) ----
  for (int idx = tid; idx < CI * 11; idx += 512) {
    int c = idx % CI, v2 = idx / CI;
    float* base = act + c * 220 + v2 * 2;
    float xin[10][2];
    #pragma unroll
    for (int t = 0; t < 10; ++t) { xin[t][0] = base[t*22]; xin[t][1] = base[t*22+1]; }
    float ya[10][2];
    #pragma unroll
    for (int q = 0; q < 10; ++q) { ya[q][0] = 0.f; ya[q][1] = 0.f; }
    #pragma unroll
    for (int t = 0; t < 10; ++t) {
      const float* tm = TmTs + t * 220 + v2 * 2;
      #pragma unroll
      for (int q = 0; q < 10; ++q) {
        ya[q][0] += tm[q*22]   * xin[t][0];
        ya[q][1] += tm[q*22+1] * xin[t][1];
      }
    }
    #pragma unroll
    for (int q = 0; q < 10; ++q) { base[q*22] = ya[q][0]; base[q*22+1] = ya[q][1]; }
  }
  __syncthreads();

  // ---- phase 3: spatial mix, in place (row private); restage wT <- cw ----
  for (int idx = tid; idx < CI * 10; idx += 512) {
    int c = idx % CI, t = idx / CI;
    float* row = act + c * 220 + t * 22;
    float yin[22];
    #pragma unroll
    for (int v = 0; v < 22; ++v) yin[v] = row[v];
    float za[22];
    #pragma unroll
    for (int w = 0; w < 22; ++w) za[w] = 0.f;
    #pragma unroll 2
    for (int v = 0; v < 22; ++v) {
      const float* ar = ATf + (t * 22 + v) * 22;
      float y0 = yin[v];
      #pragma unroll
      for (int w = 0; w < 22; ++w) za[w] += y0 * ar[w];
    }
    #pragma unroll
    for (int w = 0; w < 22; ++w) row[w] = za[w];
  }
  for (int idx = tid; idx < CI * 64; idx += 512) {
    int c = idx / 64, o = idx % 64;
    wT[idx] = (o < CO) ? cw[o * CI + c] : 0.f;
  }
  __syncthreads();

  // ---- phase 4: main channel-mix into registers, barrier, in-place write ----
  float cacc[32];
  if (tid < NT) {
    #pragma unroll
    for (int k = 0; k < 32; ++k) cacc[k] = 0.f;
    #pragma unroll 4
    for (int c = 0; c < CI; ++c) {
      const float* wr = wT + c * 64 + oo * 8;
      float4 w0 = *(const float4*)(wr);
      float4 w1 = *(const float4*)(wr + 4);
      float4 av = *(const float4*)(act + c * 220 + pp * 4);
      float wv[8] = {w0.x,w0.y,w0.z,w0.w,w1.x,w1.y,w1.z,w1.w};
      #pragma unroll
      for (int o = 0; o < 8; ++o) {
        cacc[o*4+0] += wv[o]*av.x; cacc[o*4+1] += wv[o]*av.y;
        cacc[o*4+2] += wv[o]*av.z; cacc[o*4+3] += wv[o]*av.w;
      }
    }
  }
  __syncthreads();   // all reads of act complete before overwrite
  if (tid < NT) {
    #pragma unroll
    for (int o = 0; o < 8; ++o) {
      float m = cmul[oo * 8 + o], a = cadd[oo * 8 + o];
      #pragma unroll
      for (int k = 0; k < 4; ++k) {
        float y = cacc[o*4+k]*m + a + racc[o*4+k];
        act[(oo*8+o)*220 + pp*4 + k] = (y >= 0.f) ? y : preL * y;
      }
    }
  }
  __syncthreads();
}

__global__ __launch_bounds__(512)
void enc_kernel(const float* __restrict__ x, const float* __restrict__ A,
                const float* __restrict__ Tm, const float* __restrict__ pre, EncW W,
                const float* __restrict__ qkvT, const float* __restrict__ qkv_b,
                float* __restrict__ h0_ws, float* __restrict__ k_ws,
                float* __restrict__ v_ws)
{
  __shared__ __align__(16) float act[64 * 220];   // 56320 B
  __shared__ __align__(16) float wT[64 * 64];     // 16384 B
  __shared__ __align__(16) float TmTs[2200];      //  8800 B
  __shared__ __align__(16) float ATf[4840];       // 19360 B
  __shared__ float rmul[64], radd[64], cmul[64], cadd[64];

  const int tid = threadIdx.x;
  const int b = blockIdx.x;

  for (int idx = tid; idx < 660; idx += 512) {
    int c = idx / 220, r = idx % 220, t = r / 22, v = r % 22;
    act[c * 220 + t * 22 + v] = x[(((size_t)b * 10 + t) * 22 + v) * 3 + c];
  }
  float p0 = pre[0], p1 = pre[1], p2 = pre[2], p3 = pre[3];

  gcn_layer32<3, 64>(tid, W.cw[0], W.cb[0], W.g[0], W.bt[0], W.rw[0], W.rb[0], W.rg[0], W.rbt[0],
                     Tm, A, p0, act, wT, TmTs, ATf, rmul, radd, cmul, cadd);
  gcn_layer32<64, 32>(tid, W.cw[1], W.cb[1], W.g[1], W.bt[1], W.rw[1], W.rb[1], W.rg[1], W.rbt[1],
                     Tm + 2200, A + 4840, p1, act, wT, TmTs, ATf, rmul, radd, cmul, cadd);
  gcn_layer32<32, 64>(tid, W.cw[2], W.cb[2], W.g[2], W.bt[2], W.rw[2], W.rb[2], W.rg[2], W.rbt[2],
                     Tm + 4400, A + 9680, p2, act, wT, TmTs, ATf, rmul, radd, cmul, cadd);
  gcn_layer32<64, 3>(tid, W.cw[3], W.cb[3], W.g[3], W.bt[3], W.rw[3], W.rb[3], W.rg[3], W.rbt[3],
                     Tm + 6600, A + 14520, p3, act, wT, TmTs, ATf, rmul, radd, cmul, cadd);

  // build encD[t][d=v*3+c] in act rows 3..5; store h0
  float* encD = act + 3 * 220;
  for (int idx = tid; idx < 660; idx += 512) {
    int t = idx / 66, d = idx % 66, v = d / 3, c = d % 3;
    float val = act[c * 220 + t * 22 + v];
    encD[idx] = val;
    if (t == 9) h0_ws[(size_t)b * 66 + d] = val;
  }
  __syncthreads();

  // K/V projection: qkvT[e*198+j], rows 66..131 -> k, 132..197 -> v
  for (int idx = tid; idx < 132; idx += 512) {
    int half = idx / 66, d = idx % 66;
    int row = 66 + half * 66 + d;
    float acc[10];
    #pragma unroll
    for (int t = 0; t < 10; ++t) acc[t] = 0.f;
    for (int e = 0; e < 66; ++e) {
      float w = qkvT[e * 198 + row];
      const float* er = encD + e;
      #pragma unroll
      for (int t = 0; t < 10; ++t) acc[t] += w * er[t * 66];
    }
    float bias = qkv_b[row];
    float* dst = (half ? v_ws : k_ws) + (size_t)b * 660 + d;
    #pragma unroll
    for (int t = 0; t < 10; ++t) dst[t * 66] = acc[t] + bias;
  }
}

// ------------------------- prep: transposes + lwB@ow fold (all f32) ---------

__global__ __launch_bounds__(512)
void prep_kernel(const float* __restrict__ qkv_w, const float* __restrict__ ow,
                 const float* __restrict__ ob, const float* __restrict__ lw,
                 float* __restrict__ qkvT, float* __restrict__ lwAT,
                 float* __restrict__ MT, float* __restrict__ cb2)
{
  int idx = blockIdx.x * 512 + threadIdx.x;
  if (idx < 13068) {                 // qkvT[e*198+j] = qkv_w[j*66+e]
    int e = idx / 198, j = idx % 198;
    qkvT[idx] = qkv_w[j * 66 + e];
    return;
  }
  int i2 = idx - 13068;
  if (i2 < 4356) {                   // lwAT[e*66+d] = lw[d*132+e]
    int e = i2 / 66, d = i2 % 66;
    lwAT[i2] = lw[d * 132 + e];
    return;
  }
  int i3 = i2 - 4356;
  if (i3 < 4356) {                   // MT[e*66+d] = sum_f lwB[d][f]*ow[f][e]
    int e = i3 / 66, d = i3 % 66;
    const float* lrow = lw + d * 132 + 66;
    float acc = 0.f;
    for (int f = 0; f < 66; ++f) acc += lrow[f] * ow[f * 66 + e];
    MT[i3] = acc;
    return;
  }
  int i4 = i3 - 4356;
  if (i4 < 66) {                     // cb2[d] = lwB[d] @ ob
    const float* lrow = lw + i4 * 132 + 66;
    float acc = 0.f;
    for (int f = 0; f < 66; ++f) acc += lrow[f] * ob[f];
    cb2[i4] = acc;
  }
}

// ---------------------------------------------------------------- decoder ---
// f32, transposed state layout X[e*8+r] (r = row-in-block). 6 barriers/step.

__global__ __launch_bounds__(512)
void dec_kernel(const float* __restrict__ x, const float* __restrict__ h0_ws,
                const float* __restrict__ k_ws, const float* __restrict__ v_ws,
                const float* __restrict__ gru_wi, const float* __restrict__ gru_wh,
                const float* __restrict__ gru_bi, const float* __restrict__ gru_bh,
                const float* __restrict__ qkvT, const float* __restrict__ qkv_b,
                const float* __restrict__ lwAT, const float* __restrict__ MT,
                const float* __restrict__ cb2, const float* __restrict__ lb,
                float* __restrict__ outp)
{
  __shared__ __align__(16) float WT[66 * 400];   // 105600 B: WT[e*400+jm], jm<198 wi, 198..395 wh
  __shared__ float G[396 * 9];                   //  14256 B: gates, stride-9 rows
  __shared__ __align__(16) float tpT[66 * 8];    //   2112 B each
  __shared__ __align__(16) float hsT[66 * 8];
  __shared__ __align__(16) float qT[66 * 8];
  __shared__ __align__(16) float cxT[66 * 8];
  __shared__ float attnS[240];
  __shared__ float biS[198], bhS[198], bqS[66], lbS[66];

  const int tid = threadIdx.x;
  const int b0 = blockIdx.x * 8;

  // stage transposed GRU weights (global coalesced; LDS write conflicts OK, one-time)
  for (int idx = tid; idx < 396 * 66; idx += 512) {
    int jm = idx / 66, e = idx % 66;
    float w = (jm < 198) ? gru_wi[jm * 66 + e] : gru_wh[(jm - 198) * 66 + e];
    WT[e * 400 + jm] = w;
  }
  for (int idx = tid; idx < 198; idx += 512) { biS[idx] = gru_bi[idx]; bhS[idx] = gru_bh[idx]; }
  for (int idx = tid; idx < 66; idx += 512)  { bqS[idx] = qkv_b[idx]; lbS[idx] = lb[idx] + cb2[idx]; }
  for (int idx = tid; idx < 528; idx += 512) {
    int r = idx & 7, d = idx >> 3;
    hsT[d * 8 + r] = h0_ws[(size_t)(b0 + r) * 66 + d];
    tpT[d * 8 + r] = x[(size_t)(b0 + r) * 660 + 594 + d];
  }
  __syncthreads();

  const float qscale = 1.0f / sqrtf(22.0f);

  for (int s = 0; s < 25; ++s) {
    // P1: gi[j] (jm<198, from tp) / gh[j] (jm>=198, from hs), all 8 rows each
    if (tid < 396) {
      const float* wcol = WT + tid;
      const float* base = (tid < 198) ? tpT : hsT;
      float acc[8];
      #pragma unroll
      for (int r = 0; r < 8; ++r) acc[r] = 0.f;
      #pragma unroll 6
      for (int e = 0; e < 66; ++e) {
        float w = wcol[e * 400];
        float4 a0 = *(const float4*)(base + e * 8);
        float4 a1 = *(const float4*)(base + e * 8 + 4);
        acc[0] += w * a0.x; acc[1] += w * a0.y; acc[2] += w * a0.z; acc[3] += w * a0.w;
        acc[4] += w * a1.x; acc[5] += w * a1.y; acc[6] += w * a1.z; acc[7] += w * a1.w;
      }
      int j = (tid < 198) ? tid : tid - 198;
      float bias = (tid < 198) ? biS[j] : bhS[j];
      #pragma unroll
      for (int r = 0; r < 8; ++r) G[tid * 9 + r] = acc[r] + bias;
    }
    __syncthreads();

    // P2: GRU gates -> hs
    for (int idx = tid; idx < 528; idx += 512) {
      int d = idx >> 3, r = idx & 7;
      float ir = G[d * 9 + r]         + G[(198 + d) * 9 + r];
      float iz = G[(66 + d) * 9 + r]  + G[(264 + d) * 9 + r];
      float nx = G[(132 + d) * 9 + r];
      float hn = G[(330 + d) * 9 + r];
      float rg = 1.f / (1.f + __expf(-ir));
      float zg = 1.f / (1.f + __expf(-iz));
      float t2 = __expf(2.f * (nx + rg * hn));
      float ng = 1.f - 2.f / (t2 + 1.f);        // tanh, overflow-safe
      float h = hsT[d * 8 + r];
      hsT[d * 8 + r] = (1.f - zg) * ng + zg * h;
    }
    __syncthreads();

    // P3: q = (hs @ wq.T + bq) * scale   (wq = qkvT cols 0..65, L2-hot)
    for (int idx = tid; idx < 528; idx += 512) {
      int r = idx / 66, d = idx % 66;
      float acc = 0.f;
      #pragma unroll 6
      for (int e = 0; e < 66; ++e)
        acc += qkvT[e * 198 + d] * hsT[e * 8 + r];
      qT[d * 8 + r] = (acc + bqS[d]) * qscale;
    }
    __syncthreads();

    // P4: scores + softmax fused (24 (r,h) tasks)
    if (tid < 24) {
      int r = tid / 3, h = tid % 3;
      const float* kb = k_ws + (size_t)(b0 + r) * 660 + h * 22;
      float sc[10];
      float mx = -1e30f;
      #pragma unroll
      for (int t = 0; t < 10; ++t) {
        float acc = 0.f;
        const float* kp = kb + t * 66;
        #pragma unroll
        for (int dd = 0; dd < 22; ++dd)
          acc += qT[(h * 22 + dd) * 8 + r] * kp[dd];
        sc[t] = acc;
        mx = fmaxf(mx, acc);
      }
      float sum = 0.f;
      #pragma unroll
      for (int t = 0; t < 10; ++t) { float e = __expf(sc[t] - mx); sc[t] = e; sum += e; }
      float invs = 1.f / sum;
      #pragma unroll
      for (int t = 0; t < 10; ++t) attnS[tid * 10 + t] = sc[t] * invs;
    }
    __syncthreads();

    // P5: ctx_raw = attn @ v
    for (int idx = tid; idx < 528; idx += 512) {
      int r = idx / 66, d = idx % 66, h = d / 22;
      const float* ap = attnS + (r * 3 + h) * 10;
      const float* vp = v_ws + (size_t)(b0 + r) * 660 + d;
      float acc = 0.f;
      #pragma unroll
      for (int t = 0; t < 10; ++t) acc += ap[t] * vp[t * 66];
      cxT[d * 8 + r] = acc;
    }
    __syncthreads();

    // P7: pred = lwA@hs + M@ctx_raw + (lb + lwB@ob) + tp ; out + tp update
    if (tid < 132) {
      int d = tid % 66, rq = tid / 66;     // rows rq*4 .. rq*4+3
      float acc[4];
      #pragma unroll
      for (int k = 0; k < 4; ++k) acc[k] = 0.f;
      #pragma unroll 4
      for (int e = 0; e < 66; ++e) {
        float wa = lwAT[e * 66 + d];
        float wm = MT[e * 66 + d];
        float4 hv = *(const float4*)(hsT + e * 8 + rq * 4);
        float4 cv = *(const float4*)(cxT + e * 8 + rq * 4);
        acc[0] += wa * hv.x + wm * cv.x;
        acc[1] += wa * hv.y + wm * cv.y;
        acc[2] += wa * hv.z + wm * cv.z;
        acc[3] += wa * hv.w + wm * cv.w;
      }
      #pragma unroll
      for (int k = 0; k < 4; ++k) {
        int r = rq * 4 + k;
        float pred = acc[k] + lbS[d] + tpT[d * 8 + r];
        outp[((size_t)(b0 + r) * 25 + s) * 66 + d] = pred;
        tpT[d * 8 + r] = pred;
      }
    }
    __syncthreads();
  }
}

// ----------------------------------------------------------------- launch ---

extern "C" void kernel_launch(void* const* d_in, const int* in_sizes, int n_in,
                              void* d_out, int out_size, void* d_ws, size_t ws_size,
                              hipStream_t stream) {
  (void)in_sizes; (void)n_in; (void)out_size; (void)ws_size;
  const float* x   = (const float*)d_in[0];
  const float* A   = (const float*)d_in[1];
  const float* Tm  = (const float*)d_in[2];
  const float* pre = (const float*)d_in[3];
  EncW W;
  for (int i = 0; i < 4; ++i) {
    W.cw[i]  = (const float*)d_in[4 + 8 * i + 0];
    W.cb[i]  = (const float*)d_in[4 + 8 * i + 1];
    W.g[i]   = (const float*)d_in[4 + 8 * i + 2];
    W.bt[i]  = (const float*)d_in[4 + 8 * i + 3];
    W.rw[i]  = (const float*)d_in[4 + 8 * i + 4];
    W.rb[i]  = (const float*)d_in[4 + 8 * i + 5];
    W.rg[i]  = (const float*)d_in[4 + 8 * i + 6];
    W.rbt[i] = (const float*)d_in[4 + 8 * i + 7];
  }
  const float* gru_wi = (const float*)d_in[36];
  const float* gru_wh = (const float*)d_in[37];
  const float* gru_bi = (const float*)d_in[38];
  const float* gru_bh = (const float*)d_in[39];
  const float* qkv_w  = (const float*)d_in[40];
  const float* qkv_b  = (const float*)d_in[41];
  const float* ow     = (const float*)d_in[42];
  const float* ob     = (const float*)d_in[43];
  const float* lw     = (const float*)d_in[44];
  const float* lb     = (const float*)d_in[45];

  float* wsf  = (float*)d_ws;
  float* h0   = wsf;                       // 2048*66
  float* kw   = h0 + 2048 * 66;            // 2048*660
  float* vw   = kw + 2048 * 660;           // 2048*660
  float* qkvT = vw + 2048 * 660;           // 13068
  float* lwAT = qkvT + 13068;              // 4356
  float* MT   = lwAT + 4356;               // 4356
  float* cb2  = MT + 4356;                 // 66

  prep_kernel<<<43, 512, 0, stream>>>(qkv_w, ow, ob, lw, qkvT, lwAT, MT, cb2);
  enc_kernel<<<2048, 512, 0, stream>>>(x, A, Tm, pre, W, qkvT, qkv_b, h0, kw, vw);
  dec_kernel<<<256, 512, 0, stream>>>(x, h0, kw, vw, gru_wi, gru_wh, gru_bi, gru_bh,
                                      qkvT, qkv_b, lwAT, MT, cb2, lb,
                                      (float*)d_out);
}